// Round 3
// baseline (1092.506 us; speedup 1.0000x reference)
//
#include <hip/hip_runtime.h>
#include <math.h>
#include <stdint.h>

#define E_N 19
#define H_N 32
#define T_N 2048
#define B_N 64
#define G_N 128      // 4*H gate rows per chain
#define XCHUNK 32    // timesteps staged per LDS round (per direction)
#define LOG2E 1.4426950408889634f

typedef _Float16 half2_t __attribute__((ext_vector_type(2)));

__device__ __forceinline__ float sigm_rcp(float e) {  // 1/(1+e)
    return __builtin_amdgcn_rcpf(1.0f + e);
}

// One WAVE (64-thread block) per (b,e). TWO chains per wave:
//   lanes 0..31  : direction 0 (forward time),  j = lane
//   lanes 32..63 : direction 1 (reversed time), j = lane-32
// Each lane owns ALL FOUR gate rows {i_j, f_j, g_j, o_j} of its chain:
//   - no cross-lane exchange at all (c,h update fully lane-local)
//   - c/tanh(c)/h instructions serve two chains per issue
// h broadcast via LDS: every lane writes its h (slot = lane); each 32-lane half
// re-reads its chain's 32 packed fp16 h as 4x ds_read_b128 (same address within
// each half -> broadcast; the two halves hit disjoint banks -> conflict-free).
//
// amdgpu_waves_per_eu(1,1): license the full VGPR file. R2 regression: without
// this the allocator targeted 8 waves/EU (52 VGPRs) and spilled the 64 packed
// weight regs to scratch, reloading them EVERY step (FETCH_SIZE 40->63 MB).
__global__ __launch_bounds__(64)
__attribute__((amdgpu_waves_per_eu(1, 1)))
void lstm_chain_kernel(
    const float* __restrict__ x,     // [B, T, E]
    const float* __restrict__ w_ih,  // [E, 2, 4H]
    const float* __restrict__ w_hh,  // [E, 2, 4H, H]
    const float* __restrict__ b_ih,  // [E, 2, 4H]
    const float* __restrict__ b_hh,  // [E, 2, 4H]
    float* __restrict__ hT)          // [B, E, 2, H]
{
    const int lane = threadIdx.x;
    const int be   = blockIdx.x;          // b*E + e
    const int b    = be / E_N;
    const int e    = be - b * E_N;
    const int j    = lane & 31;
    const int half = lane >> 5;           // == direction d
    const int ed   = e * 2 + half;

    // ---- load fp32 weights for rows j, j+32, j+64, j+96 (i,f,g,o), pack fp16 ----
    const float* wbase = w_hh + (size_t)ed * G_N * H_N;
    uint32_t wp[4][16];                   // 64 VGPRs of packed fp16 weight pairs
    #pragma unroll
    for (int r = 0; r < 4; ++r) {
        const float* wr = wbase + (size_t)(j + 32 * r) * H_N;
        #pragma unroll
        for (int m = 0; m < 16; ++m) {
            float2 v = ((const float2*)wr)[m];
            half2_t p = { (_Float16)v.x, (_Float16)v.y };
            wp[r][m] = __builtin_bit_cast(uint32_t, p);
        }
    }
    float wih[4], bias[4];
    #pragma unroll
    for (int r = 0; r < 4; ++r) {
        const int row = j + 32 * r;
        wih[r]  = w_ih[(size_t)ed * G_N + row];
        bias[r] = b_ih[(size_t)ed * G_N + row] + b_hh[(size_t)ed * G_N + row];
    }

    // LDS: h (64 fp16: [0..31] chain d0, [32..63] chain d1) + x chunk per dir
    __shared__ __align__(16) uint16_t hbuf[64];
    __shared__ float xbuf[64];            // [0..31] fwd steps, [32..63] rev steps

    hbuf[lane] = 0;
    float c = 0.0f, h = 0.0f;

    const float* xbase = x + (size_t)b * T_N * E_N + e;

    // prefetch first x chunk: this half's step t = j (physical index per dir)
    float xreg;
    {
        const int tphys = half ? (T_N - 1 - j) : j;
        xreg = xbase[(size_t)tphys * E_N];
    }

    for (int t0 = 0; t0 < T_N; t0 += XCHUNK) {
        // PIN: keep the 64 packed weight regs live across the inner loop (no-op).
        #pragma unroll
        for (int r = 0; r < 4; ++r)
            #pragma unroll
            for (int m = 0; m < 16; ++m)
                asm volatile("" : "+v"(wp[r][m]));

        // stage this chunk (already in xreg), then issue next chunk's global load
        xbuf[lane] = xreg;
        if (t0 + XCHUNK < T_N) {
            const int tn    = t0 + XCHUNK + j;
            const int tphys = half ? (T_N - 1 - tn) : tn;
            xreg = xbase[(size_t)tphys * E_N];
        }

        #pragma unroll 1
        for (int tl = 0; tl < XCHUNK; ++tl) {
            // broadcast reads: this half's 32 h fp16 (4 x b128) + x (b32)
            const uint4 q0 = ((const uint4*)hbuf)[half * 4 + 0];
            const uint4 q1 = ((const uint4*)hbuf)[half * 4 + 1];
            const uint4 q2 = ((const uint4*)hbuf)[half * 4 + 2];
            const uint4 q3 = ((const uint4*)hbuf)[half * 4 + 3];
            const float sx = xbuf[(half << 5) + tl];

            uint32_t hp[16];
            hp[0]=q0.x; hp[1]=q0.y; hp[2]=q0.z; hp[3]=q0.w;
            hp[4]=q1.x; hp[5]=q1.y; hp[6]=q1.z; hp[7]=q1.w;
            hp[8]=q2.x; hp[9]=q2.y; hp[10]=q2.z; hp[11]=q2.w;
            hp[12]=q3.x; hp[13]=q3.y; hp[14]=q3.z; hp[15]=q3.w;

            // 4 gate dots, each split 2 x 8-deep (8 independent fdot2 chains)
            float acc[4], accb[4];
            #pragma unroll
            for (int r = 0; r < 4; ++r) {
                acc[r]  = fmaf(sx, wih[r], bias[r]);
                accb[r] = 0.0f;
            }
            #pragma unroll
            for (int m = 0; m < 8; ++m) {
                #pragma unroll
                for (int r = 0; r < 4; ++r) {
                    acc[r]  = __builtin_amdgcn_fdot2(
                        __builtin_bit_cast(half2_t, hp[m]),
                        __builtin_bit_cast(half2_t, wp[r][m]),   acc[r],  false);
                    accb[r] = __builtin_amdgcn_fdot2(
                        __builtin_bit_cast(half2_t, hp[m + 8]),
                        __builtin_bit_cast(half2_t, wp[r][m + 8]), accb[r], false);
                }
            }
            const float gi = acc[0] + accb[0];
            const float gf = acc[1] + accb[1];
            const float gg = acc[2] + accb[2];
            const float go = acc[3] + accb[3];

            // activations (PyTorch gate order i,f,g,o)
            const float si = sigm_rcp(__builtin_amdgcn_exp2f(gi * (-LOG2E)));
            const float sf = sigm_rcp(__builtin_amdgcn_exp2f(gf * (-LOG2E)));
            const float tg = fmaf(2.0f, sigm_rcp(
                __builtin_amdgcn_exp2f(gg * (-2.0f * LOG2E))), -1.0f);   // tanh(g)
            const float so = sigm_rcp(__builtin_amdgcn_exp2f(go * (-LOG2E)));

            c = fmaf(sf, c, si * tg);                                    // f*c + i*g
            const float tc = fmaf(2.0f, sigm_rcp(
                __builtin_amdgcn_exp2f(c * (-2.0f * LOG2E))), -1.0f);    // tanh(c)
            h = so * tc;                                                 // o * tanh(c)

            // publish h: slot = lane (2 lanes/bank -> free)
            hbuf[lane] = __builtin_bit_cast(uint16_t, (_Float16)h);
        }
    }

    // every lane holds a valid final h for its (chain, j)
    hT[((size_t)(b * E_N + e) * 2 + half) * H_N + j] = h;
}

// LayerNorm over 64 feats per (b,e), mean over e, FC -> out[b]. One wave per b.
__global__ __launch_bounds__(64) void head_kernel(
    const float* __restrict__ hT,      // [B, E, 64]
    const float* __restrict__ ln_gamma,// [E, 64]
    const float* __restrict__ ln_beta, // [E, 64]
    const float* __restrict__ fc_w,    // [64]
    const float* __restrict__ fc_b,    // [1]
    float* __restrict__ out)           // [B]
{
    const int b = blockIdx.x;
    const int f = threadIdx.x; // 0..63

    float acc = 0.0f;
    for (int e = 0; e < E_N; ++e) {
        const float v = hT[(size_t)(b * E_N + e) * 64 + f];
        float s = v, s2 = v * v;
        #pragma unroll
        for (int off = 32; off > 0; off >>= 1) {
            s  += __shfl_xor(s,  off);
            s2 += __shfl_xor(s2, off);
        }
        const float mean = s * (1.0f / 64.0f);
        const float var  = s2 * (1.0f / 64.0f) - mean * mean;
        const float inv  = rsqrtf(var + 1e-5f);
        acc += (v - mean) * inv * ln_gamma[e * 64 + f] + ln_beta[e * 64 + f];
    }
    float contrib = (acc * (1.0f / (float)E_N)) * fc_w[f];
    #pragma unroll
    for (int off = 32; off > 0; off >>= 1) contrib += __shfl_xor(contrib, off);
    if (f == 0) out[b] = contrib + fc_b[0];
}

extern "C" void kernel_launch(void* const* d_in, const int* in_sizes, int n_in,
                              void* d_out, int out_size, void* d_ws, size_t ws_size,
                              hipStream_t stream) {
    const float* x        = (const float*)d_in[0];
    const float* w_ih     = (const float*)d_in[1];
    const float* w_hh     = (const float*)d_in[2];
    const float* b_ih     = (const float*)d_in[3];
    const float* b_hh     = (const float*)d_in[4];
    const float* ln_gamma = (const float*)d_in[5];
    const float* ln_beta  = (const float*)d_in[6];
    const float* fc_w     = (const float*)d_in[7];
    const float* fc_b     = (const float*)d_in[8];
    float* out = (float*)d_out;
    float* hT  = (float*)d_ws;  // B*E*2*H floats

    lstm_chain_kernel<<<B_N * E_N, 64, 0, stream>>>(x, w_ih, w_hh, b_ih, b_hh, hT);
    head_kernel<<<B_N, 64, 0, stream>>>(hT, ln_gamma, ln_beta, fc_w, fc_b, out);
}

// Round 4
// 1029.091 us; speedup vs baseline: 1.0616x; 1.0616x over previous
//
#include <hip/hip_runtime.h>
#include <math.h>
#include <stdint.h>

#define E_N 19
#define H_N 32
#define T_N 2048
#define B_N 64
#define G_N 128      // 4*H gate rows per chain
#define XCHUNK 32    // timesteps staged per LDS round (per direction)
#define LOG2E 1.4426950408889634f

typedef _Float16 half2_t __attribute__((ext_vector_type(2)));

__device__ __forceinline__ float sigm_rcp(float e) {  // 1/(1+e)
    return __builtin_amdgcn_rcpf(1.0f + e);
}

// One WAVE (64-thread block) per (b,e). TWO chains per wave:
//   lanes 0..31  : direction 0 (forward time),  j = lane
//   lanes 32..63 : direction 1 (reversed time), j = lane-32
// Each lane owns ALL FOUR gate rows {i_j, f_j, g_j, o_j} of its chain:
//   - no cross-lane exchange at all (c,h update fully lane-local)
//   - c/tanh(c)/h instructions serve two chains per issue
// h broadcast via LDS: every lane writes its h (slot = lane); each 32-lane half
// re-reads its chain's 32 packed fp16 h as 4x ds_read_b128 (same address within
// each half -> broadcast; the two halves hit disjoint banks -> conflict-free).
//
// waves_per_eu(2) [min only]: licenses 256 VGPRs (no spill of the 64 packed
// weight regs — R2's failure) while leaving runtime residency UNBOUNDED.
// R3's (1,1) capped residency at 4 blocks/CU -> grid of 1216 ran in TWO
// sequential passes (dur 2x, occupancy 7%). Grid needs 5 blocks/CU in spots.
__global__ __launch_bounds__(64)
__attribute__((amdgpu_waves_per_eu(2)))
void lstm_chain_kernel(
    const float* __restrict__ x,     // [B, T, E]
    const float* __restrict__ w_ih,  // [E, 2, 4H]
    const float* __restrict__ w_hh,  // [E, 2, 4H, H]
    const float* __restrict__ b_ih,  // [E, 2, 4H]
    const float* __restrict__ b_hh,  // [E, 2, 4H]
    float* __restrict__ hT)          // [B, E, 2, H]
{
    const int lane = threadIdx.x;
    const int be   = blockIdx.x;          // b*E + e
    const int b    = be / E_N;
    const int e    = be - b * E_N;
    const int j    = lane & 31;
    const int half = lane >> 5;           // == direction d
    const int ed   = e * 2 + half;

    // ---- load fp32 weights for rows j, j+32, j+64, j+96 (i,f,g,o), pack fp16 ----
    const float* wbase = w_hh + (size_t)ed * G_N * H_N;
    uint32_t wp[4][16];                   // 64 VGPRs of packed fp16 weight pairs
    #pragma unroll
    for (int r = 0; r < 4; ++r) {
        const float* wr = wbase + (size_t)(j + 32 * r) * H_N;
        #pragma unroll
        for (int m = 0; m < 16; ++m) {
            float2 v = ((const float2*)wr)[m];
            half2_t p = { (_Float16)v.x, (_Float16)v.y };
            wp[r][m] = __builtin_bit_cast(uint32_t, p);
        }
    }
    float wih[4], bias[4];
    #pragma unroll
    for (int r = 0; r < 4; ++r) {
        const int row = j + 32 * r;
        wih[r]  = w_ih[(size_t)ed * G_N + row];
        bias[r] = b_ih[(size_t)ed * G_N + row] + b_hh[(size_t)ed * G_N + row];
    }

    // LDS: h (64 fp16: [0..31] chain d0, [32..63] chain d1) + x chunk per dir
    __shared__ __align__(16) uint16_t hbuf[64];
    __shared__ float xbuf[64];            // [0..31] fwd steps, [32..63] rev steps

    hbuf[lane] = 0;
    float c = 0.0f, h = 0.0f;

    const float* xbase = x + (size_t)b * T_N * E_N + e;

    // prefetch first x chunk: this half's step t = j (physical index per dir)
    float xreg;
    {
        const int tphys = half ? (T_N - 1 - j) : j;
        xreg = xbase[(size_t)tphys * E_N];
    }

    for (int t0 = 0; t0 < T_N; t0 += XCHUNK) {
        // PIN: keep the 64 packed weight regs live across the inner loop (no-op).
        #pragma unroll
        for (int r = 0; r < 4; ++r)
            #pragma unroll
            for (int m = 0; m < 16; ++m)
                asm volatile("" : "+v"(wp[r][m]));

        // stage this chunk (already in xreg), then issue next chunk's global load
        xbuf[lane] = xreg;
        if (t0 + XCHUNK < T_N) {
            const int tn    = t0 + XCHUNK + j;
            const int tphys = half ? (T_N - 1 - tn) : tn;
            xreg = xbase[(size_t)tphys * E_N];
        }

        #pragma unroll 1
        for (int tl = 0; tl < XCHUNK; ++tl) {
            // broadcast reads: this half's 32 h fp16 (4 x b128) + x (b32)
            const uint4 q0 = ((const uint4*)hbuf)[half * 4 + 0];
            const uint4 q1 = ((const uint4*)hbuf)[half * 4 + 1];
            const uint4 q2 = ((const uint4*)hbuf)[half * 4 + 2];
            const uint4 q3 = ((const uint4*)hbuf)[half * 4 + 3];
            const float sx = xbuf[(half << 5) + tl];

            uint32_t hp[16];
            hp[0]=q0.x; hp[1]=q0.y; hp[2]=q0.z; hp[3]=q0.w;
            hp[4]=q1.x; hp[5]=q1.y; hp[6]=q1.z; hp[7]=q1.w;
            hp[8]=q2.x; hp[9]=q2.y; hp[10]=q2.z; hp[11]=q2.w;
            hp[12]=q3.x; hp[13]=q3.y; hp[14]=q3.z; hp[15]=q3.w;

            // 4 gate dots, each split 4 x 4-deep (16 independent fdot2 chains):
            // shortens the dependent-latency of the matvec; issue is cheap at
            // ~1.2 waves/SIMD.
            float a0[4], a1[4], a2[4], a3[4];
            #pragma unroll
            for (int r = 0; r < 4; ++r) {
                a0[r] = fmaf(sx, wih[r], bias[r]);
                a1[r] = 0.0f; a2[r] = 0.0f; a3[r] = 0.0f;
            }
            #pragma unroll
            for (int m = 0; m < 4; ++m) {
                #pragma unroll
                for (int r = 0; r < 4; ++r) {
                    a0[r] = __builtin_amdgcn_fdot2(
                        __builtin_bit_cast(half2_t, hp[m]),
                        __builtin_bit_cast(half2_t, wp[r][m]),      a0[r], false);
                    a1[r] = __builtin_amdgcn_fdot2(
                        __builtin_bit_cast(half2_t, hp[m + 4]),
                        __builtin_bit_cast(half2_t, wp[r][m + 4]),  a1[r], false);
                    a2[r] = __builtin_amdgcn_fdot2(
                        __builtin_bit_cast(half2_t, hp[m + 8]),
                        __builtin_bit_cast(half2_t, wp[r][m + 8]),  a2[r], false);
                    a3[r] = __builtin_amdgcn_fdot2(
                        __builtin_bit_cast(half2_t, hp[m + 12]),
                        __builtin_bit_cast(half2_t, wp[r][m + 12]), a3[r], false);
                }
            }
            const float gi = (a0[0] + a1[0]) + (a2[0] + a3[0]);
            const float gf = (a0[1] + a1[1]) + (a2[1] + a3[1]);
            const float gg = (a0[2] + a1[2]) + (a2[2] + a3[2]);
            const float go = (a0[3] + a1[3]) + (a2[3] + a3[3]);

            // activations (PyTorch gate order i,f,g,o)
            const float si = sigm_rcp(__builtin_amdgcn_exp2f(gi * (-LOG2E)));
            const float sf = sigm_rcp(__builtin_amdgcn_exp2f(gf * (-LOG2E)));
            const float tg = fmaf(2.0f, sigm_rcp(
                __builtin_amdgcn_exp2f(gg * (-2.0f * LOG2E))), -1.0f);   // tanh(g)
            const float so = sigm_rcp(__builtin_amdgcn_exp2f(go * (-LOG2E)));

            c = fmaf(sf, c, si * tg);                                    // f*c + i*g
            const float tc = fmaf(2.0f, sigm_rcp(
                __builtin_amdgcn_exp2f(c * (-2.0f * LOG2E))), -1.0f);    // tanh(c)
            h = so * tc;                                                 // o * tanh(c)

            // publish h: slot = lane (2 lanes/bank -> free)
            hbuf[lane] = __builtin_bit_cast(uint16_t, (_Float16)h);
        }
    }

    // every lane holds a valid final h for its (chain, j)
    hT[((size_t)(b * E_N + e) * 2 + half) * H_N + j] = h;
}

// LayerNorm over 64 feats per (b,e), mean over e, FC -> out[b]. One wave per b.
__global__ __launch_bounds__(64) void head_kernel(
    const float* __restrict__ hT,      // [B, E, 64]
    const float* __restrict__ ln_gamma,// [E, 64]
    const float* __restrict__ ln_beta, // [E, 64]
    const float* __restrict__ fc_w,    // [64]
    const float* __restrict__ fc_b,    // [1]
    float* __restrict__ out)           // [B]
{
    const int b = blockIdx.x;
    const int f = threadIdx.x; // 0..63

    float acc = 0.0f;
    for (int e = 0; e < E_N; ++e) {
        const float v = hT[(size_t)(b * E_N + e) * 64 + f];
        float s = v, s2 = v * v;
        #pragma unroll
        for (int off = 32; off > 0; off >>= 1) {
            s  += __shfl_xor(s,  off);
            s2 += __shfl_xor(s2, off);
        }
        const float mean = s * (1.0f / 64.0f);
        const float var  = s2 * (1.0f / 64.0f) - mean * mean;
        const float inv  = rsqrtf(var + 1e-5f);
        acc += (v - mean) * inv * ln_gamma[e * 64 + f] + ln_beta[e * 64 + f];
    }
    float contrib = (acc * (1.0f / (float)E_N)) * fc_w[f];
    #pragma unroll
    for (int off = 32; off > 0; off >>= 1) contrib += __shfl_xor(contrib, off);
    if (f == 0) out[b] = contrib + fc_b[0];
}

extern "C" void kernel_launch(void* const* d_in, const int* in_sizes, int n_in,
                              void* d_out, int out_size, void* d_ws, size_t ws_size,
                              hipStream_t stream) {
    const float* x        = (const float*)d_in[0];
    const float* w_ih     = (const float*)d_in[1];
    const float* w_hh     = (const float*)d_in[2];
    const float* b_ih     = (const float*)d_in[3];
    const float* b_hh     = (const float*)d_in[4];
    const float* ln_gamma = (const float*)d_in[5];
    const float* ln_beta  = (const float*)d_in[6];
    const float* fc_w     = (const float*)d_in[7];
    const float* fc_b     = (const float*)d_in[8];
    float* out = (float*)d_out;
    float* hT  = (float*)d_ws;  // B*E*2*H floats

    lstm_chain_kernel<<<B_N * E_N, 64, 0, stream>>>(x, w_ih, w_hh, b_ih, b_hh, hT);
    head_kernel<<<B_N, 64, 0, stream>>>(hT, ln_gamma, ln_beta, fc_w, fc_b, out);
}

// Round 5
// 966.208 us; speedup vs baseline: 1.1307x; 1.0651x over previous
//
#include <hip/hip_runtime.h>
#include <math.h>
#include <stdint.h>

#define E_N 19
#define H_N 32
#define T_N 2048
#define B_N 64
#define G_N 128      // 4*H gate rows per chain
#define XCHUNK 32    // timesteps staged per LDS round (per direction)
#define LOG2E 1.4426950408889634f

typedef _Float16 half2_t __attribute__((ext_vector_type(2)));

__device__ __forceinline__ float sigm_rcp(float e) {  // 1/(1+e)
    return __builtin_amdgcn_rcpf(1.0f + e);
}

// One WAVE (64-thread block) per (b,e). TWO chains per wave:
//   lanes 0..31  : direction 0 (forward time),  j = lane
//   lanes 32..63 : direction 1 (reversed time), j = lane-32
// Each lane owns ALL FOUR gate rows {i_j, f_j, g_j, o_j} of its chain:
// no cross-lane exchange; c/h update fully lane-local; scalar tail shared by
// two chains per issue.
//
// REGISTER LICENSE — the whole game (R2-R4 post-mortems):
//   WRITE_SIZE flat at 304 KB across all rounds => never any scratch spill.
//   Under-licensed allocators instead RE-LOAD the 64 packed weight regs from
//   global inside the inner loop (read-only remat: FETCH +21 MB, 52/72 VGPRs).
//   Open-max waves_per_eu(2) went occupancy-greedy (72 VGPRs). Closed form
//   (4,4) => hard cap 512/4 = 128 VGPRs: live set ~103 fits, residency
//   license 4/SIMD covers the 4.75 blocks/CU demand in one pass.
__global__ __launch_bounds__(64)
__attribute__((amdgpu_waves_per_eu(4, 4)))
void lstm_chain_kernel(
    const float* __restrict__ x,     // [B, T, E]
    const float* __restrict__ w_ih,  // [E, 2, 4H]
    const float* __restrict__ w_hh,  // [E, 2, 4H, H]
    const float* __restrict__ b_ih,  // [E, 2, 4H]
    const float* __restrict__ b_hh,  // [E, 2, 4H]
    float* __restrict__ hT)          // [B, E, 2, H]
{
    const int lane = threadIdx.x;
    const int be   = blockIdx.x;          // b*E + e
    const int b    = be / E_N;
    const int e    = be - b * E_N;
    const int j    = lane & 31;
    const int half = lane >> 5;           // == direction d
    const int ed   = e * 2 + half;

    // ---- load fp32 weights for rows j, j+32, j+64, j+96 (i,f,g,o), pack fp16 ----
    const float* wbase = w_hh + (size_t)ed * G_N * H_N;
    uint32_t wp[4][16];                   // 64 VGPRs of packed fp16 weight pairs
    #pragma unroll
    for (int r = 0; r < 4; ++r) {
        const float* wr = wbase + (size_t)(j + 32 * r) * H_N;
        #pragma unroll
        for (int m = 0; m < 16; ++m) {
            float2 v = ((const float2*)wr)[m];
            half2_t p = { (_Float16)v.x, (_Float16)v.y };
            wp[r][m] = __builtin_bit_cast(uint32_t, p);
        }
    }
    float wih[4], bias[4];
    #pragma unroll
    for (int r = 0; r < 4; ++r) {
        const int row = j + 32 * r;
        wih[r]  = w_ih[(size_t)ed * G_N + row];
        bias[r] = b_ih[(size_t)ed * G_N + row] + b_hh[(size_t)ed * G_N + row];
    }

    // LDS: h (64 fp16: [0..31] chain d0, [32..63] chain d1) + x chunk per dir
    __shared__ __align__(16) uint16_t hbuf[64];
    __shared__ float xbuf[64];            // [0..31] fwd steps, [32..63] rev steps

    hbuf[lane] = 0;
    float c = 0.0f, h = 0.0f;

    const float* xbase = x + (size_t)b * T_N * E_N + e;

    // prefetch first x chunk: this half's step t = j (physical index per dir)
    float xreg;
    {
        const int tphys = half ? (T_N - 1 - j) : j;
        xreg = xbase[(size_t)tphys * E_N];
    }

    for (int t0 = 0; t0 < T_N; t0 += XCHUNK) {
        // PIN: keep the 64 packed weight regs live across the inner loop (no-op).
        #pragma unroll
        for (int r = 0; r < 4; ++r)
            #pragma unroll
            for (int m = 0; m < 16; ++m)
                asm volatile("" : "+v"(wp[r][m]));

        // stage this chunk (already in xreg), then issue next chunk's global load
        xbuf[lane] = xreg;
        if (t0 + XCHUNK < T_N) {
            const int tn    = t0 + XCHUNK + j;
            const int tphys = half ? (T_N - 1 - tn) : tn;
            xreg = xbase[(size_t)tphys * E_N];
        }

        #pragma unroll 1
        for (int tl = 0; tl < XCHUNK; ++tl) {
            // broadcast reads: this half's 32 h fp16 (4 x b128) + x (b32)
            const uint4 q0 = ((const uint4*)hbuf)[half * 4 + 0];
            const uint4 q1 = ((const uint4*)hbuf)[half * 4 + 1];
            const uint4 q2 = ((const uint4*)hbuf)[half * 4 + 2];
            const uint4 q3 = ((const uint4*)hbuf)[half * 4 + 3];
            const float sx = xbuf[(half << 5) + tl];

            uint32_t hp[16];
            hp[0]=q0.x; hp[1]=q0.y; hp[2]=q0.z; hp[3]=q0.w;
            hp[4]=q1.x; hp[5]=q1.y; hp[6]=q1.z; hp[7]=q1.w;
            hp[8]=q2.x; hp[9]=q2.y; hp[10]=q2.z; hp[11]=q2.w;
            hp[12]=q3.x; hp[13]=q3.y; hp[14]=q3.z; hp[15]=q3.w;

            // 4 gate dots, each split 2 x 8-deep (8 independent fdot2 chains):
            // keeps the live accumulator set at 8 regs (headroom under the
            // 128-reg cap is worth more than ~25cy of chain latency here).
            float acc[4], accb[4];
            #pragma unroll
            for (int r = 0; r < 4; ++r) {
                acc[r]  = fmaf(sx, wih[r], bias[r]);
                accb[r] = 0.0f;
            }
            #pragma unroll
            for (int m = 0; m < 8; ++m) {
                #pragma unroll
                for (int r = 0; r < 4; ++r) {
                    acc[r]  = __builtin_amdgcn_fdot2(
                        __builtin_bit_cast(half2_t, hp[m]),
                        __builtin_bit_cast(half2_t, wp[r][m]),   acc[r],  false);
                    accb[r] = __builtin_amdgcn_fdot2(
                        __builtin_bit_cast(half2_t, hp[m + 8]),
                        __builtin_bit_cast(half2_t, wp[r][m + 8]), accb[r], false);
                }
            }
            const float gi = acc[0] + accb[0];
            const float gf = acc[1] + accb[1];
            const float gg = acc[2] + accb[2];
            const float go = acc[3] + accb[3];

            // activations (PyTorch gate order i,f,g,o)
            const float si = sigm_rcp(__builtin_amdgcn_exp2f(gi * (-LOG2E)));
            const float sf = sigm_rcp(__builtin_amdgcn_exp2f(gf * (-LOG2E)));
            const float tg = fmaf(2.0f, sigm_rcp(
                __builtin_amdgcn_exp2f(gg * (-2.0f * LOG2E))), -1.0f);   // tanh(g)
            const float so = sigm_rcp(__builtin_amdgcn_exp2f(go * (-LOG2E)));

            c = fmaf(sf, c, si * tg);                                    // f*c + i*g
            const float tc = fmaf(2.0f, sigm_rcp(
                __builtin_amdgcn_exp2f(c * (-2.0f * LOG2E))), -1.0f);    // tanh(c)
            h = so * tc;                                                 // o * tanh(c)

            // publish h: slot = lane (2 lanes/bank -> free)
            hbuf[lane] = __builtin_bit_cast(uint16_t, (_Float16)h);
        }
    }

    // every lane holds a valid final h for its (chain, j)
    hT[((size_t)(b * E_N + e) * 2 + half) * H_N + j] = h;
}

// LayerNorm over 64 feats per (b,e), mean over e, FC -> out[b]. One wave per b.
__global__ __launch_bounds__(64) void head_kernel(
    const float* __restrict__ hT,      // [B, E, 64]
    const float* __restrict__ ln_gamma,// [E, 64]
    const float* __restrict__ ln_beta, // [E, 64]
    const float* __restrict__ fc_w,    // [64]
    const float* __restrict__ fc_b,    // [1]
    float* __restrict__ out)           // [B]
{
    const int b = blockIdx.x;
    const int f = threadIdx.x; // 0..63

    float acc = 0.0f;
    for (int e = 0; e < E_N; ++e) {
        const float v = hT[(size_t)(b * E_N + e) * 64 + f];
        float s = v, s2 = v * v;
        #pragma unroll
        for (int off = 32; off > 0; off >>= 1) {
            s  += __shfl_xor(s,  off);
            s2 += __shfl_xor(s2, off);
        }
        const float mean = s * (1.0f / 64.0f);
        const float var  = s2 * (1.0f / 64.0f) - mean * mean;
        const float inv  = rsqrtf(var + 1e-5f);
        acc += (v - mean) * inv * ln_gamma[e * 64 + f] + ln_beta[e * 64 + f];
    }
    float contrib = (acc * (1.0f / (float)E_N)) * fc_w[f];
    #pragma unroll
    for (int off = 32; off > 0; off >>= 1) contrib += __shfl_xor(contrib, off);
    if (f == 0) out[b] = contrib + fc_b[0];
}

extern "C" void kernel_launch(void* const* d_in, const int* in_sizes, int n_in,
                              void* d_out, int out_size, void* d_ws, size_t ws_size,
                              hipStream_t stream) {
    const float* x        = (const float*)d_in[0];
    const float* w_ih     = (const float*)d_in[1];
    const float* w_hh     = (const float*)d_in[2];
    const float* b_ih     = (const float*)d_in[3];
    const float* b_hh     = (const float*)d_in[4];
    const float* ln_gamma = (const float*)d_in[5];
    const float* ln_beta  = (const float*)d_in[6];
    const float* fc_w     = (const float*)d_in[7];
    const float* fc_b     = (const float*)d_in[8];
    float* out = (float*)d_out;
    float* hT  = (float*)d_ws;  // B*E*2*H floats

    lstm_chain_kernel<<<B_N * E_N, 64, 0, stream>>>(x, w_ih, w_hh, b_ih, b_hh, hT);
    head_kernel<<<B_N, 64, 0, stream>>>(hT, ln_gamma, ln_beta, fc_w, fc_b, out);
}